// Round 6
// baseline (143.058 us; speedup 1.0000x reference)
//
#include <hip/hip_runtime.h>

#define Bn 32
#define Tn 16384
#define Ln 16
#define Sn 128
#define Hn 512
#define Cn 10
#define Kn 48
#define TOUT 16369
#define CH 1024
#define NCH 16
#define XGRP 132           // 16-B groups per channel row in LDS (1056 bf16 elems)
#define XBP 8224           // xbf dword pitch per (b,ch): (16384 + 64 pad) / 2

typedef short  s16x8  __attribute__((ext_vector_type(8)));
typedef float  f32x16 __attribute__((ext_vector_type(16)));

static __device__ __forceinline__ unsigned short f2bf(float f) {
    union { float f; unsigned int u; } v; v.f = f;
    unsigned int r = v.u + 0x7FFF + ((v.u >> 16) & 1);   // RNE
    return (unsigned short)(r >> 16);
}
static __device__ __forceinline__ unsigned int pk(float a, float b) {
    return (unsigned int)f2bf(a) | ((unsigned int)f2bf(b) << 16);
}
// XOR swizzle on 16-B groups within each aligned 128-B block (size-preserving)
static __device__ __forceinline__ int swz(int g) { return g ^ ((g >> 3) & 7); }

static __device__ __forceinline__ s16x8 mk_a(unsigned int d0, unsigned int d1,
                                             unsigned int d2, unsigned int d3) {
    union { unsigned int u[4]; s16x8 v; } t;
    t.u[0] = d0; t.u[1] = d1; t.u[2] = d2; t.u[3] = d3;
    return t.v;
}

// ------------------------------------------------------------------ prologue
// Precompute (once, memory-bound): bf16(-2*sh) rows, shsq, winsq w/ tail mask,
// bf16(x) w/ zero pad. Keeps ALL conversion/window math out of dist_kernel.
__global__ __launch_bounds__(256) void prep_kernel(const float* __restrict__ x,
                                                   const float* __restrict__ sh,
                                                   unsigned int* __restrict__ shb,
                                                   float* __restrict__ shsq_g,
                                                   float* __restrict__ wsq_g,
                                                   unsigned int* __restrict__ xbf) {
    const int tid = threadIdx.x;
    if (blockIdx.x == 0) {
        if (tid < Sn) {
            const float4* r4 = (const float4*)(sh + tid * Kn);
            float v[48]; float q = 0.f;
            #pragma unroll
            for (int c = 0; c < 12; ++c) {
                const float4 t = r4[c];
                v[4*c] = t.x; v[4*c+1] = t.y; v[4*c+2] = t.z; v[4*c+3] = t.w;
                q = fmaf(t.x, t.x, q); q = fmaf(t.y, t.y, q);
                q = fmaf(t.z, t.z, q); q = fmaf(t.w, t.w, q);
            }
            shsq_g[tid] = q;
            uint4* dst = (uint4*)(shb + tid * 24);
            #pragma unroll
            for (int c = 0; c < 6; ++c) {
                uint4 o;
                o.x = pk(-2.f*v[8*c  ], -2.f*v[8*c+1]);
                o.y = pk(-2.f*v[8*c+2], -2.f*v[8*c+3]);
                o.z = pk(-2.f*v[8*c+4], -2.f*v[8*c+5]);
                o.w = pk(-2.f*v[8*c+6], -2.f*v[8*c+7]);
                dst[c] = o;
            }
        } else {
            const int idx = tid - 128;          // zero the 64-elem xbf tail pads
            const int p = idx >> 1, hh = idx & 1;
            if (p < 96) {
                uint4 z = {0u, 0u, 0u, 0u};
                uint4* d = (uint4*)(xbf + p * XBP + 8192 + hh * 16);
                d[0] = z; d[1] = z; d[2] = z; d[3] = z;
            }
        }
        return;
    }
    // winsq + x->bf16: block bid-1 handles (b, 2048-t slab); thread owns 8 t
    const int bid = blockIdx.x - 1;
    const int b  = bid >> 3;
    const int t0 = ((bid & 7) << 11) + 8 * tid;
    float q[8] = {0.f,0.f,0.f,0.f,0.f,0.f,0.f,0.f};
    #pragma unroll
    for (int ch = 0; ch < 3; ++ch) {
        const float* xs = x + (b * 3 + ch) * Tn + t0;
        float wv[24];
        if (t0 + 24 <= Tn) {
            const float4* x4 = (const float4*)xs;
            #pragma unroll
            for (int c = 0; c < 6; ++c) {
                const float4 t = x4[c];
                wv[4*c] = t.x; wv[4*c+1] = t.y; wv[4*c+2] = t.z; wv[4*c+3] = t.w;
            }
        } else {
            #pragma unroll
            for (int k = 0; k < 24; ++k) wv[k] = (t0 + k < Tn) ? xs[k] : 0.f;
        }
        float s = 0.f;
        #pragma unroll
        for (int l = 0; l < 16; ++l) s = fmaf(wv[l], wv[l], s);
        q[0] += s;
        #pragma unroll
        for (int j = 1; j < 8; ++j) {
            s = s - wv[j-1]*wv[j-1] + wv[j+15]*wv[j+15];
            q[j] += s;
        }
        uint4 o = { pk(wv[0],wv[1]), pk(wv[2],wv[3]), pk(wv[4],wv[5]), pk(wv[6],wv[7]) };
        *(uint4*)(xbf + (b * 3 + ch) * XBP + (t0 >> 1)) = o;
    }
    float4 o0, o1;
    o0.x = (t0+0 >= TOUT) ? 1e30f : q[0]; o0.y = (t0+1 >= TOUT) ? 1e30f : q[1];
    o0.z = (t0+2 >= TOUT) ? 1e30f : q[2]; o0.w = (t0+3 >= TOUT) ? 1e30f : q[3];
    o1.x = (t0+4 >= TOUT) ? 1e30f : q[4]; o1.y = (t0+5 >= TOUT) ? 1e30f : q[5];
    o1.z = (t0+6 >= TOUT) ? 1e30f : q[6]; o1.w = (t0+7 >= TOUT) ? 1e30f : q[7];
    float4* wd = (float4*)(wsq_g + b * Tn + t0);
    wd[0] = o0; wd[1] = o1;
}

// ---------------------------------------------------------------- distance
// Pure copy-in + MFMA + min epilogue. Single-phase x in LDS; per-tile A-frags
// derived by compile-time funnel shifts (tile i = 8*(w&1) + rr + 512*(w>>1),
// so each lane's 16-elem window is rr-invariant -> loaded ONCE per wave).
// (256,2): 256-reg/wave budget; steady live set ~90 regs, peak ~180.
__global__ __launch_bounds__(256, 2) void dist_kernel(const unsigned int* __restrict__ shb,
                                                      const float* __restrict__ shsq_g,
                                                      const float* __restrict__ wsq_g,
                                                      const unsigned int* __restrict__ xbf,
                                                      float* __restrict__ partial) {
    __shared__ unsigned int xph[3 * XGRP * 4];   // 6336 B (one phase, 3 channels)
    __shared__ float wsq[16 * 64];               // 4096 B, transposed [t&15][t>>4 + 32*ihi]
    __shared__ float wavemin[4 * Sn];            // 2048 B

    const int tid   = threadIdx.x;
    const int b     = blockIdx.x >> 4;
    const int chunk = blockIdx.x & 15;
    const int tb    = chunk * CH;
    const int lane  = tid & 63;
    const int w     = tid >> 6;
    const int n     = lane & 31;     // MFMA row (A) / col (B,C)
    const int h     = lane >> 5;     // k-half select

    // ---- 1) B-fragments + shsq: direct vector loads from prepped ws (L2-hot)
    s16x8 bfr[3][4];
    float shsqv[4];
    #pragma unroll
    for (int st = 0; st < 4; ++st) {
        const uint4* base = (const uint4*)(shb + (st * 32 + n) * 24);
        #pragma unroll
        for (int kk = 0; kk < 3; ++kk) {
            const uint4 t = base[kk * 2 + h];
            bfr[kk][st] = mk_a(t.x, t.y, t.z, t.w);
        }
        shsqv[st] = shsq_g[st * 32 + n];
    }

    // ---- 2) x staging: pure bf16 copy, 2x uint4 per active thread
    if (tid < 198) {
        const int ch = tid / 66, j = tid - ch * 66;   // span j: elems [16j, 16j+16)
        const uint4* src = (const uint4*)(xbf + (b * 3 + ch) * XBP + ((tb + 16 * j) >> 1));
        const uint4 lo = src[0], hi = src[1];
        const int gb = ch * XGRP + 2 * j;
        *(uint4*)((char*)xph + (swz(gb)     << 4)) = lo;
        *(uint4*)((char*)xph + (swz(gb + 1) << 4)) = hi;
    }

    // ---- 3) winsq staging: float4 load + transposed scatter
    {
        const float4 v = *(const float4*)(wsq_g + b * Tn + tb + 4 * tid);
        const int t0 = 4 * tid;
        wsq[((t0    ) & 15) * 64 + ((t0    ) >> 4)] = v.x;
        wsq[((t0 + 1) & 15) * 64 + ((t0 + 1) >> 4)] = v.y;
        wsq[((t0 + 2) & 15) * 64 + ((t0 + 2) >> 4)] = v.z;
        wsq[((t0 + 3) & 15) * 64 + ((t0 + 3) >> 4)] = v.w;
    }
    __syncthreads();

    // ---- 4) load each lane's rr-invariant 16-elem window per channel (once)
    unsigned int uwin[3][8];
    {
        const int gbase = (w & 1) + ((w >> 1) << 6);
        #pragma unroll
        for (int ch = 0; ch < 3; ++ch) {
            const int g = gbase + ch * XGRP + 2 * n + h;
            const uint4 lo = *(const uint4*)((const char*)xph + (swz(g)     << 4));
            const uint4 hi = *(const uint4*)((const char*)xph + (swz(g + 1) << 4));
            uwin[ch][0] = lo.x; uwin[ch][1] = lo.y; uwin[ch][2] = lo.z; uwin[ch][3] = lo.w;
            uwin[ch][4] = hi.x; uwin[ch][5] = hi.y; uwin[ch][6] = hi.z; uwin[ch][7] = hi.w;
        }
    }

    // ---- 5) main loop: 8 tiles, A-frags by static funnel shift rr
    float mcol[4] = {1e30f, 1e30f, 1e30f, 1e30f};
    const f32x16 zero16 = {0.f, 0.f, 0.f, 0.f, 0.f, 0.f, 0.f, 0.f,
                           0.f, 0.f, 0.f, 0.f, 0.f, 0.f, 0.f, 0.f};
    #pragma unroll
    for (int rr = 0; rr < 8; ++rr) {
        const int i = 8 * (w & 1) + rr + ((w >> 1) << 9);
        s16x8 a[3];
        #pragma unroll
        for (int ch = 0; ch < 3; ++ch) {
            unsigned int d[4];
            #pragma unroll
            for (int k = 0; k < 4; ++k) {
                if ((rr & 1) == 0)
                    d[k] = uwin[ch][(rr >> 1) + k];
                else
                    d[k] = (uwin[ch][(rr >> 1) + k] >> 16) |
                           (uwin[ch][(rr >> 1) + k + 1] << 16);   // v_alignbit
            }
            a[ch] = mk_a(d[0], d[1], d[2], d[3]);
        }

        f32x16 acc[4];
        #pragma unroll
        for (int st = 0; st < 4; ++st) {
            acc[st] = __builtin_amdgcn_mfma_f32_32x32x16_bf16(a[0], bfr[0][st], zero16, 0, 0, 0);
            acc[st] = __builtin_amdgcn_mfma_f32_32x32x16_bf16(a[1], bfr[1][st], acc[st], 0, 0, 0);
            acc[st] = __builtin_amdgcn_mfma_f32_32x32x16_bf16(a[2], bfr[2][st], acc[st], 0, 0, 0);
        }

        const int ilow = i & 15, ihi = i >> 9;
        float4 wq[4];
        #pragma unroll
        for (int q = 0; q < 4; ++q)
            wq[q] = *(const float4*)&wsq[ilow * 64 + 8 * q + 4 * h + 32 * ihi];

        #pragma unroll
        for (int st = 0; st < 4; ++st)
            #pragma unroll
            for (int reg = 0; reg < 16; reg += 2) {
                const float u = acc[st][reg]     + ((const float*)&wq[reg >> 2])[(reg & 3)];
                const float v = acc[st][reg + 1] + ((const float*)&wq[reg >> 2])[(reg & 3) + 1];
                mcol[st] = fminf(fminf(mcol[st], u), v);   // v_min3
            }
    }

    // ---- 6) reduce: +shsq once; lanes n / n+32 share column s = st*32+n
    #pragma unroll
    for (int st = 0; st < 4; ++st) {
        float mm = mcol[st] + shsqv[st];
        mm = fminf(mm, __shfl_xor(mm, 32, 64));
        if (h == 0) wavemin[w * Sn + st * 32 + n] = mm;
    }
    __syncthreads();
    if (tid < Sn) {
        const float mm = fminf(fminf(wavemin[tid], wavemin[Sn + tid]),
                               fminf(wavemin[2 * Sn + tid], wavemin[3 * Sn + tid]));
        partial[(b * NCH + chunk) * Sn + tid] = mm;
    }
}

// ------------------------------------------- final min over chunks + MLP head
__global__ __launch_bounds__(512) void mlp_kernel(const float* __restrict__ partial,
                                                  const float* __restrict__ W1,
                                                  const float* __restrict__ b1,
                                                  const float* __restrict__ W2,
                                                  const float* __restrict__ b2,
                                                  float* __restrict__ out) {
    __shared__ float pmin[4][Sn];
    __shared__ float db[Sn];
    __shared__ float hb[Hn];
    __shared__ float part[Cn][32];
    const int b = blockIdx.x, tid = threadIdx.x;

    {
        const int s = tid & 127, g = tid >> 7;
        const float* pp = partial + (b * NCH + g * 4) * Sn + s;
        float m = pp[0];
        #pragma unroll
        for (int c = 1; c < 4; ++c) m = fminf(m, pp[c * Sn]);
        pmin[g][s] = m;
    }
    __syncthreads();
    if (tid < Sn) {
        const float m = fminf(fminf(pmin[0][tid], pmin[1][tid]),
                              fminf(pmin[2][tid], pmin[3][tid]));
        db[tid] = m;
        out[b * Sn + tid] = m;             // distance output
    }
    __syncthreads();

    float a = b1[tid];
    const float4* w1r = (const float4*)(W1 + tid * Sn);
    const float4* dbv = (const float4*)db;
    #pragma unroll
    for (int i = 0; i < Sn / 4; ++i) {
        const float4 wv = w1r[i];
        const float4 dv = dbv[i];
        a = fmaf(dv.x, wv.x, a); a = fmaf(dv.y, wv.y, a);
        a = fmaf(dv.z, wv.z, a); a = fmaf(dv.w, wv.w, a);
    }
    hb[tid] = fmaxf(a, 0.0f);
    __syncthreads();

    if (tid < Cn * 32) {
        const int c = tid >> 5, p = tid & 31;
        float acc = 0.f;
        #pragma unroll
        for (int i = 0; i < Hn / 32; ++i)
            acc = fmaf(hb[p + 32 * i], W2[c * Hn + p + 32 * i], acc);
        part[c][p] = acc;
    }
    __syncthreads();
    if (tid < Cn) {
        float acc = b2[tid];
        #pragma unroll
        for (int p = 0; p < 32; ++p) acc += part[tid][p];
        out[Bn * Sn + b * Cn + tid] = acc; // classification output
    }
}

// ----------------------------------------------------------------- launcher
extern "C" void kernel_launch(void* const* d_in, const int* in_sizes, int n_in,
                              void* d_out, int out_size, void* d_ws, size_t ws_size,
                              hipStream_t stream) {
    const float* x  = (const float*)d_in[0];
    const float* sh = (const float*)d_in[1];
    const float* W1 = (const float*)d_in[2];
    const float* b1 = (const float*)d_in[3];
    const float* W2 = (const float*)d_in[4];
    const float* b2 = (const float*)d_in[5];
    float* out = (float*)d_out;

    char* wsb = (char*)d_ws;
    float*        partial = (float*)wsb;                    // 262144 B
    unsigned int* shb     = (unsigned int*)(wsb + 262144);  //  12288 B
    float*        shsq_g  = (float*)(wsb + 274432);         //    512 B
    float*        wsq_g   = (float*)(wsb + 278528);         //   2 MiB
    unsigned int* xbf     = (unsigned int*)(wsb + 2375680); //   ~3 MiB

    prep_kernel<<<257, 256, 0, stream>>>(x, sh, shb, shsq_g, wsq_g, xbf);
    dist_kernel<<<Bn * NCH, 256, 0, stream>>>(shb, shsq_g, wsq_g, xbf, partial);
    mlp_kernel<<<Bn, 512, 0, stream>>>(partial, W1, b1, W2, b2, out);
}

// Round 7
// 101.462 us; speedup vs baseline: 1.4100x; 1.4100x over previous
//
#include <hip/hip_runtime.h>

#define Bn 32
#define Tn 16384
#define Ln 16
#define Sn 128
#define Hn 512
#define Cn 10
#define Kn 48
#define TOUT 16369
#define CH 1024
#define NCH 16
#define XBP 8224           // dwords per phase row in global (8192 + 32 zero pad)
#define NGRP 3168          // 24 rows x 132 16-B groups in dist LDS

typedef short  s16x8  __attribute__((ext_vector_type(8)));
typedef float  f32x16 __attribute__((ext_vector_type(16)));

static __device__ __forceinline__ unsigned short f2bf(float f) {
    union { float f; unsigned int u; } v; v.f = f;
    unsigned int r = v.u + 0x7FFF + ((v.u >> 16) & 1);   // RNE
    return (unsigned short)(r >> 16);
}
static __device__ __forceinline__ unsigned int pk(float a, float b) {
    return (unsigned int)f2bf(a) | ((unsigned int)f2bf(b) << 16);
}
static __device__ __forceinline__ unsigned int pk2(unsigned short a, unsigned short b) {
    return (unsigned int)a | ((unsigned int)b << 16);
}
// XOR swizzle on 16-B groups within each aligned 128-B block (bijective)
static __device__ __forceinline__ int swz(int g) { return g ^ ((g >> 3) & 7); }

static __device__ __forceinline__ s16x8 mk_a(unsigned int d0, unsigned int d1,
                                             unsigned int d2, unsigned int d3) {
    union { unsigned int u[4]; s16x8 v; } t;
    t.u[0] = d0; t.u[1] = d1; t.u[2] = d2; t.u[3] = d3;
    return t.v;
}

// ------------------------------------------------------------------ prologue
// Precompute everything once (memory-bound):
//   shb: bf16(-2*sh) rows in B-frag order; shsq: fp32 row norms
//   wsq_g: fp32 window norms with 1e30 tail mask
//   xg: 8 PHASE-SHIFTED bf16 copies of x (xg[b][p][ch][u] = bf16 x[b,ch,u+p]),
//       zero-padded — dist_kernel then stages pure uint4 copies, zero VALU.
__global__ __launch_bounds__(256) void prep_kernel(const float* __restrict__ x,
                                                   const float* __restrict__ sh,
                                                   unsigned int* __restrict__ shb,
                                                   float* __restrict__ shsq_g,
                                                   float* __restrict__ wsq_g,
                                                   unsigned int* __restrict__ xg) {
    const int tid = threadIdx.x;
    if (blockIdx.x == 0) {
        if (tid < Sn) {
            const float4* r4 = (const float4*)(sh + tid * Kn);
            float v[48]; float q = 0.f;
            #pragma unroll
            for (int c = 0; c < 12; ++c) {
                const float4 t = r4[c];
                v[4*c] = t.x; v[4*c+1] = t.y; v[4*c+2] = t.z; v[4*c+3] = t.w;
                q = fmaf(t.x, t.x, q); q = fmaf(t.y, t.y, q);
                q = fmaf(t.z, t.z, q); q = fmaf(t.w, t.w, q);
            }
            shsq_g[tid] = q;
            uint4* dst = (uint4*)(shb + tid * 24);
            #pragma unroll
            for (int c = 0; c < 6; ++c) {
                uint4 o;
                o.x = pk(-2.f*v[8*c  ], -2.f*v[8*c+1]);
                o.y = pk(-2.f*v[8*c+2], -2.f*v[8*c+3]);
                o.z = pk(-2.f*v[8*c+4], -2.f*v[8*c+5]);
                o.w = pk(-2.f*v[8*c+6], -2.f*v[8*c+7]);
                dst[c] = o;
            }
        } else {
            // zero the 32-dword tail pad of all 768 phase rows
            const int idx = tid - 128;
            const uint4 z = {0u, 0u, 0u, 0u};
            for (int r = idx; r < 768; r += 128) {
                uint4* d = (uint4*)(xg + r * XBP + 8192);
                #pragma unroll
                for (int q = 0; q < 8; ++q) d[q] = z;
            }
        }
        return;
    }
    // x -> 8 phase rows + winsq; block handles (b, 2048-t slab), thread owns 8 t
    const int bid = blockIdx.x - 1;
    const int b  = bid >> 3;
    const int t0 = ((bid & 7) << 11) + 8 * tid;
    float q[8] = {0.f,0.f,0.f,0.f,0.f,0.f,0.f,0.f};
    #pragma unroll
    for (int ch = 0; ch < 3; ++ch) {
        const float* xs = x + (b * 3 + ch) * Tn + t0;
        float wv[24];
        if (t0 + 24 <= Tn) {
            const float4* x4 = (const float4*)xs;
            #pragma unroll
            for (int c = 0; c < 6; ++c) {
                const float4 t = x4[c];
                wv[4*c] = t.x; wv[4*c+1] = t.y; wv[4*c+2] = t.z; wv[4*c+3] = t.w;
            }
        } else {
            #pragma unroll
            for (int k = 0; k < 24; ++k) wv[k] = (t0 + k < Tn) ? xs[k] : 0.f;
        }
        float s = 0.f;
        #pragma unroll
        for (int l = 0; l < 16; ++l) s = fmaf(wv[l], wv[l], s);
        q[0] += s;
        #pragma unroll
        for (int j = 1; j < 8; ++j) {
            s = s - wv[j-1]*wv[j-1] + wv[j+15]*wv[j+15];
            q[j] += s;
        }
        unsigned short bf[24];
        #pragma unroll
        for (int k = 0; k < 24; ++k) bf[k] = f2bf(wv[k]);
        #pragma unroll
        for (int p = 0; p < 8; ++p) {
            uint4 o = { pk2(bf[p  ], bf[p+1]), pk2(bf[p+2], bf[p+3]),
                        pk2(bf[p+4], bf[p+5]), pk2(bf[p+6], bf[p+7]) };
            *(uint4*)(xg + ((b * 8 + p) * 3 + ch) * XBP + (t0 >> 1)) = o;
        }
    }
    float4 o0, o1;
    o0.x = (t0+0 >= TOUT) ? 1e30f : q[0]; o0.y = (t0+1 >= TOUT) ? 1e30f : q[1];
    o0.z = (t0+2 >= TOUT) ? 1e30f : q[2]; o0.w = (t0+3 >= TOUT) ? 1e30f : q[3];
    o1.x = (t0+4 >= TOUT) ? 1e30f : q[4]; o1.y = (t0+5 >= TOUT) ? 1e30f : q[5];
    o1.z = (t0+6 >= TOUT) ? 1e30f : q[6]; o1.w = (t0+7 >= TOUT) ? 1e30f : q[7];
    float4* wd = (float4*)(wsq_g + b * Tn + t0);
    wd[0] = o0; wd[1] = o1;
}

// ---------------------------------------------------------------- distance
// Pure copy-in + per-tile ds_read_b128 + MFMA + min epilogue (the no-spill R2
// shape). Persistent regs: bfr 48 + shsqv/mcol/addr (~70 arch) + 64 AGPR acc.
// #pragma unroll 2 caps hoisted temporaries (full unroll spilled: R6 165MB wr).
__global__ __launch_bounds__(256, 2) void dist_kernel(const unsigned int* __restrict__ shb,
                                                      const float* __restrict__ shsq_g,
                                                      const float* __restrict__ wsq_g,
                                                      const unsigned int* __restrict__ xg,
                                                      float* __restrict__ partial) {
    __shared__ unsigned int xph[NGRP * 4];       // 50688 B: 24 rows x 132 groups
    __shared__ float wsq[16 * 64];               //  4096 B, [t&15][t>>4]
    __shared__ float wavemin[4 * Sn];            //  2048 B

    const int tid   = threadIdx.x;
    const int b     = blockIdx.x >> 4;
    const int chunk = blockIdx.x & 15;
    const int tb    = chunk * CH;
    const int lane  = tid & 63;
    const int w     = tid >> 6;
    const int n     = lane & 31;     // MFMA row (A) / col (B,C)
    const int h     = lane >> 5;     // k-half select

    // ---- 1) B-fragments + shsq (vector loads, L2-hot)
    s16x8 bfr[3][4];
    float shsqv[4];
    #pragma unroll
    for (int st = 0; st < 4; ++st) {
        const uint4* base = (const uint4*)(shb + (st * 32 + n) * 24);
        #pragma unroll
        for (int kk = 0; kk < 3; ++kk) {
            const uint4 t = base[kk * 2 + h];
            bfr[kk][st] = mk_a(t.x, t.y, t.z, t.w);
        }
        shsqv[st] = shsq_g[st * 32 + n];
    }

    // ---- 2) x staging: pure uint4 copy of 24 pre-shifted phase rows
    {
        const unsigned int* xgb = xg + b * 24 * XBP + (tb >> 1);
        for (int g = tid; g < NGRP; g += 256) {
            const int r = g / 132, c = g - r * 132;
            const uint4 v = *(const uint4*)(xgb + r * XBP + (c << 2));
            *(uint4*)((char*)xph + (swz(g) << 4)) = v;
        }
    }

    // ---- 3) winsq staging: float4 load + transposed scatter
    {
        const float4 v = *(const float4*)(wsq_g + b * Tn + tb + 4 * tid);
        const int t0 = 4 * tid;
        wsq[((t0    ) & 15) * 64 + ((t0    ) >> 4)] = v.x;
        wsq[((t0 + 1) & 15) * 64 + ((t0 + 1) >> 4)] = v.y;
        wsq[((t0 + 2) & 15) * 64 + ((t0 + 2) >> 4)] = v.z;
        wsq[((t0 + 3) & 15) * 64 + ((t0 + 3) >> 4)] = v.w;
    }
    __syncthreads();

    // ---- 4) main loop: 8 tiles/wave, A-frags straight from LDS
    float mcol[4] = {1e30f, 1e30f, 1e30f, 1e30f};
    const f32x16 zero16 = {0.f, 0.f, 0.f, 0.f, 0.f, 0.f, 0.f, 0.f,
                           0.f, 0.f, 0.f, 0.f, 0.f, 0.f, 0.f, 0.f};
    #pragma unroll 2
    for (int rr = 0; rr < 8; ++rr) {
        const int tau = 8 * w + rr;
        const int i   = (tau & 15) + ((tau >> 4) << 9);   // {0..15} u {512..527}
        const int p   = i & 7;
        const int gb  = (i >> 3) + 2 * n + h;             // group within row
        const int r0  = p * 3 * 132;
        const s16x8 a0 = *(const s16x8*)((const char*)xph + (swz(r0 + gb)       << 4));
        const s16x8 a1 = *(const s16x8*)((const char*)xph + (swz(r0 + 132 + gb) << 4));
        const s16x8 a2 = *(const s16x8*)((const char*)xph + (swz(r0 + 264 + gb) << 4));

        f32x16 acc[4];
        #pragma unroll
        for (int st = 0; st < 4; ++st) {
            acc[st] = __builtin_amdgcn_mfma_f32_32x32x16_bf16(a0, bfr[0][st], zero16, 0, 0, 0);
            acc[st] = __builtin_amdgcn_mfma_f32_32x32x16_bf16(a1, bfr[1][st], acc[st], 0, 0, 0);
            acc[st] = __builtin_amdgcn_mfma_f32_32x32x16_bf16(a2, bfr[2][st], acc[st], 0, 0, 0);
        }

        const int ilow = i & 15, ihi = i >> 9;
        float4 wq[4];
        #pragma unroll
        for (int q = 0; q < 4; ++q)
            wq[q] = *(const float4*)&wsq[ilow * 64 + 8 * q + 4 * h + 32 * ihi];

        #pragma unroll
        for (int st = 0; st < 4; ++st)
            #pragma unroll
            for (int reg = 0; reg < 16; reg += 2) {
                const float u = acc[st][reg]     + ((const float*)&wq[reg >> 2])[(reg & 3)];
                const float v = acc[st][reg + 1] + ((const float*)&wq[reg >> 2])[(reg & 3) + 1];
                mcol[st] = fminf(fminf(mcol[st], u), v);   // v_min3
            }
    }

    // ---- 5) reduce: +shsq once; lanes n / n+32 share column s = st*32+n
    #pragma unroll
    for (int st = 0; st < 4; ++st) {
        float mm = mcol[st] + shsqv[st];
        mm = fminf(mm, __shfl_xor(mm, 32, 64));
        if (h == 0) wavemin[w * Sn + st * 32 + n] = mm;
    }
    __syncthreads();
    if (tid < Sn) {
        const float mm = fminf(fminf(wavemin[tid], wavemin[Sn + tid]),
                               fminf(wavemin[2 * Sn + tid], wavemin[3 * Sn + tid]));
        partial[(b * NCH + chunk) * Sn + tid] = mm;
    }
}

// ------------------------------------------- final min over chunks + MLP head
__global__ __launch_bounds__(512) void mlp_kernel(const float* __restrict__ partial,
                                                  const float* __restrict__ W1,
                                                  const float* __restrict__ b1,
                                                  const float* __restrict__ W2,
                                                  const float* __restrict__ b2,
                                                  float* __restrict__ out) {
    __shared__ float pmin[4][Sn];
    __shared__ float db[Sn];
    __shared__ float hb[Hn];
    __shared__ float part[Cn][32];
    const int b = blockIdx.x, tid = threadIdx.x;

    {
        const int s = tid & 127, g = tid >> 7;
        const float* pp = partial + (b * NCH + g * 4) * Sn + s;
        float m = pp[0];
        #pragma unroll
        for (int c = 1; c < 4; ++c) m = fminf(m, pp[c * Sn]);
        pmin[g][s] = m;
    }
    __syncthreads();
    if (tid < Sn) {
        const float m = fminf(fminf(pmin[0][tid], pmin[1][tid]),
                              fminf(pmin[2][tid], pmin[3][tid]));
        db[tid] = m;
        out[b * Sn + tid] = m;             // distance output
    }
    __syncthreads();

    float a = b1[tid];
    const float4* w1r = (const float4*)(W1 + tid * Sn);
    const float4* dbv = (const float4*)db;
    #pragma unroll
    for (int i = 0; i < Sn / 4; ++i) {
        const float4 wv = w1r[i];
        const float4 dv = dbv[i];
        a = fmaf(dv.x, wv.x, a); a = fmaf(dv.y, wv.y, a);
        a = fmaf(dv.z, wv.z, a); a = fmaf(dv.w, wv.w, a);
    }
    hb[tid] = fmaxf(a, 0.0f);
    __syncthreads();

    if (tid < Cn * 32) {
        const int c = tid >> 5, p = tid & 31;
        float acc = 0.f;
        #pragma unroll
        for (int i = 0; i < Hn / 32; ++i)
            acc = fmaf(hb[p + 32 * i], W2[c * Hn + p + 32 * i], acc);
        part[c][p] = acc;
    }
    __syncthreads();
    if (tid < Cn) {
        float acc = b2[tid];
        #pragma unroll
        for (int p = 0; p < 32; ++p) acc += part[tid][p];
        out[Bn * Sn + b * Cn + tid] = acc; // classification output
    }
}

// ----------------------------------------------------------------- launcher
extern "C" void kernel_launch(void* const* d_in, const int* in_sizes, int n_in,
                              void* d_out, int out_size, void* d_ws, size_t ws_size,
                              hipStream_t stream) {
    const float* x  = (const float*)d_in[0];
    const float* sh = (const float*)d_in[1];
    const float* W1 = (const float*)d_in[2];
    const float* b1 = (const float*)d_in[3];
    const float* W2 = (const float*)d_in[4];
    const float* b2 = (const float*)d_in[5];
    float* out = (float*)d_out;

    char* wsb = (char*)d_ws;
    float*        partial = (float*)wsb;                    // 262144 B
    unsigned int* shb     = (unsigned int*)(wsb + 262144);  //  12288 B
    float*        shsq_g  = (float*)(wsb + 274432);         //    512 B
    float*        wsq_g   = (float*)(wsb + 278528);         //   2 MiB
    unsigned int* xg      = (unsigned int*)(wsb + 2375680); //  ~25 MiB (768 rows x XBP dw)

    prep_kernel<<<257, 256, 0, stream>>>(x, sh, shb, shsq_g, wsq_g, xg);
    dist_kernel<<<Bn * NCH, 256, 0, stream>>>(shb, shsq_g, wsq_g, xg, partial);
    mlp_kernel<<<Bn, 512, 0, stream>>>(partial, W1, b1, W2, b2, out);
}

// Round 8
// 99.742 us; speedup vs baseline: 1.4343x; 1.0172x over previous
//
#include <hip/hip_runtime.h>

#define Bn 32
#define Tn 16384
#define Ln 16
#define Sn 128
#define Hn 512
#define Cn 10
#define Kn 48
#define TOUT 16369
#define CH 1024
#define NCH 16
#define XBP 8224           // dwords per phase row in global (8192 + 32 zero pad)

typedef short  s16x8  __attribute__((ext_vector_type(8)));
typedef float  f32x16 __attribute__((ext_vector_type(16)));

static __device__ __forceinline__ unsigned short f2bf(float f) {
    union { float f; unsigned int u; } v; v.f = f;
    unsigned int r = v.u + 0x7FFF + ((v.u >> 16) & 1);   // RNE
    return (unsigned short)(r >> 16);
}
static __device__ __forceinline__ unsigned int pk(float a, float b) {
    return (unsigned int)f2bf(a) | ((unsigned int)f2bf(b) << 16);
}
static __device__ __forceinline__ unsigned int pk2(unsigned short a, unsigned short b) {
    return (unsigned int)a | ((unsigned int)b << 16);
}
static __device__ __forceinline__ s16x8 mk_a(uint4 t) {
    union { uint4 u; s16x8 v; } c; c.u = t; return c.v;
}

// ------------------------------------------------------------------ prologue
// Precompute once (memory-bound, 2 blocks/CU):
//   shb:  bf16(-2*sh) rows (B-frag order) ; shsq: fp32 row norms
//   wsqT: window norms TRANSPOSED wsqT[b][t&15][t>>4], 1e30 tail mask
//   xg:   8 phase-shifted bf16 copies, xg[((b*8+p)*3+ch)*XBP + t] = x[b,ch,t+p]
__global__ __launch_bounds__(256) void prep_kernel(const float* __restrict__ x,
                                                   const float* __restrict__ sh,
                                                   unsigned int* __restrict__ shb,
                                                   float* __restrict__ shsq_g,
                                                   float* __restrict__ wsqT,
                                                   unsigned int* __restrict__ xg) {
    const int tid = threadIdx.x;
    if (blockIdx.x == 0) {
        if (tid < Sn) {
            const float4* r4 = (const float4*)(sh + tid * Kn);
            float v[48]; float q = 0.f;
            #pragma unroll
            for (int c = 0; c < 12; ++c) {
                const float4 t = r4[c];
                v[4*c] = t.x; v[4*c+1] = t.y; v[4*c+2] = t.z; v[4*c+3] = t.w;
                q = fmaf(t.x, t.x, q); q = fmaf(t.y, t.y, q);
                q = fmaf(t.z, t.z, q); q = fmaf(t.w, t.w, q);
            }
            shsq_g[tid] = q;
            uint4* dst = (uint4*)(shb + tid * 24);
            #pragma unroll
            for (int c = 0; c < 6; ++c) {
                uint4 o;
                o.x = pk(-2.f*v[8*c  ], -2.f*v[8*c+1]);
                o.y = pk(-2.f*v[8*c+2], -2.f*v[8*c+3]);
                o.z = pk(-2.f*v[8*c+4], -2.f*v[8*c+5]);
                o.w = pk(-2.f*v[8*c+6], -2.f*v[8*c+7]);
                dst[c] = o;
            }
        } else {
            const int idx = tid - 128;          // zero the 32-dword pad of 768 rows
            const uint4 z = {0u, 0u, 0u, 0u};
            for (int r = idx; r < 768; r += 128) {
                uint4* d = (uint4*)(xg + r * XBP + 8192);
                #pragma unroll
                for (int q = 0; q < 8; ++q) d[q] = z;
            }
        }
        return;
    }
    // blocks 1..512: (b, 1024-t slab); thread owns 4 t
    const int bid = blockIdx.x - 1;
    const int b    = bid >> 4;
    const int t0   = ((bid & 15) << 10) + 4 * tid;
    float q[4] = {0.f, 0.f, 0.f, 0.f};
    #pragma unroll
    for (int ch = 0; ch < 3; ++ch) {
        const float* xs = x + (b * 3 + ch) * Tn + t0;
        float wv[20];
        if (t0 + 20 <= Tn) {
            const float4* x4 = (const float4*)xs;
            #pragma unroll
            for (int c = 0; c < 5; ++c) {
                const float4 t = x4[c];
                wv[4*c] = t.x; wv[4*c+1] = t.y; wv[4*c+2] = t.z; wv[4*c+3] = t.w;
            }
        } else {
            #pragma unroll
            for (int k = 0; k < 20; ++k) wv[k] = (t0 + k < Tn) ? xs[k] : 0.f;
        }
        float s = 0.f;
        #pragma unroll
        for (int l = 0; l < 16; ++l) s = fmaf(wv[l], wv[l], s);
        q[0] += s;
        #pragma unroll
        for (int j = 1; j < 4; ++j) {
            s = s - wv[j-1]*wv[j-1] + wv[j+15]*wv[j+15];
            q[j] += s;
        }
        unsigned short bf[20];
        #pragma unroll
        for (int k = 0; k < 20; ++k) bf[k] = f2bf(wv[k]);
        unsigned int* xrow = xg + (b * 24 + ch) * XBP + (t0 >> 1);
        #pragma unroll
        for (int p = 0; p < 8; ++p) {
            uint2 o = { pk2(bf[p], bf[p+1]), pk2(bf[p+2], bf[p+3]) };
            *(uint2*)(xrow + p * 3 * XBP) = o;
        }
    }
    const int r0 = t0 & 15, col = t0 >> 4;     // r0 in {0,4,8,12}; col same for c=0..3
    float* wrow = wsqT + b * (16 * 1024) + col;
    #pragma unroll
    for (int c = 0; c < 4; ++c)
        wrow[(r0 + c) * 1024] = (t0 + c >= TOUT) ? 1e30f : q[c];
}

// ---------------------------------------------------------------- distance
// NO LDS data path: A-frags and winsq come straight from prepped global
// (phase layout gives 16B-aligned loads; per-block working set ~26 KB -> L1).
// S split across 2 blocks: live regs ~130 (bfr24 + acc32 + wq16 + a12 + misc)
// -> (256,3) cap 170 with ~40 margin -> 12 waves/CU (vs 8 before).
__global__ __launch_bounds__(256, 3) void dist_kernel(const unsigned int* __restrict__ shb,
                                                      const float* __restrict__ shsq_g,
                                                      const float* __restrict__ wsqT,
                                                      const unsigned int* __restrict__ xg,
                                                      float* __restrict__ partial) {
    __shared__ float wavemin[4 * 64];            // 1024 B (only LDS use: reduce)

    const int tid   = threadIdx.x;
    const int b     = blockIdx.x >> 5;
    const int rem   = blockIdx.x & 31;
    const int chunk = rem >> 1;
    const int half  = rem & 1;                   // S-half: columns half*64 .. +63
    const int tb    = chunk * CH;
    const int lane  = tid & 63;
    const int w     = tid >> 6;
    const int n     = lane & 31;                 // MFMA row (A) / col (B,C)
    const int h     = lane >> 5;                 // k-half select

    // ---- 1) B-fragments + shsq (6 b128 + 2 scalar loads, L2-hot)
    s16x8 bfr[3][2];
    float shsqv[2];
    #pragma unroll
    for (int st = 0; st < 2; ++st) {
        const int s = half * 64 + st * 32 + n;
        const uint4* base = (const uint4*)(shb + s * 24);
        #pragma unroll
        for (int kk = 0; kk < 3; ++kk)
            bfr[kk][st] = mk_a(base[kk * 2 + h]);
        shsqv[st] = shsq_g[s];
    }

    // ---- 2) main loop: 8 tiles/wave, everything from global
    float mcol[2] = {1e30f, 1e30f};
    const f32x16 zero16 = {0.f, 0.f, 0.f, 0.f, 0.f, 0.f, 0.f, 0.f,
                           0.f, 0.f, 0.f, 0.f, 0.f, 0.f, 0.f, 0.f};
    const unsigned int* xgb  = xg + b * 24 * XBP + (tb >> 1);
    const float*        wrowb = wsqT + b * (16 * 1024) + (tb >> 4);

    #pragma unroll 2
    for (int rr = 0; rr < 8; ++rr) {
        const int tau = 8 * w + rr;
        const int i   = (tau & 15) + ((tau >> 4) << 9);   // {0..15} u {512..527}
        const int p   = i & 7;
        const unsigned int* arow = xgb + p * 3 * XBP + (((i & ~7) >> 1) + 8 * n + 4 * h);
        const s16x8 a0 = mk_a(*(const uint4*)(arow));
        const s16x8 a1 = mk_a(*(const uint4*)(arow + XBP));
        const s16x8 a2 = mk_a(*(const uint4*)(arow + 2 * XBP));

        f32x16 acc[2];
        #pragma unroll
        for (int st = 0; st < 2; ++st) {
            acc[st] = __builtin_amdgcn_mfma_f32_32x32x16_bf16(a0, bfr[0][st], zero16, 0, 0, 0);
            acc[st] = __builtin_amdgcn_mfma_f32_32x32x16_bf16(a1, bfr[1][st], acc[st], 0, 0, 0);
            acc[st] = __builtin_amdgcn_mfma_f32_32x32x16_bf16(a2, bfr[2][st], acc[st], 0, 0, 0);
        }

        // winsq: 4 aligned broadcast b128 loads (cols m = 8q+4h .. +3)
        const float* wrow = wrowb + (i & 15) * 1024 + ((i >> 9) << 5);
        float4 wq[4];
        #pragma unroll
        for (int q = 0; q < 4; ++q)
            wq[q] = *(const float4*)(wrow + 8 * q + 4 * h);

        #pragma unroll
        for (int st = 0; st < 2; ++st)
            #pragma unroll
            for (int reg = 0; reg < 16; reg += 2) {
                const float u = acc[st][reg]     + ((const float*)&wq[reg >> 2])[(reg & 3)];
                const float v = acc[st][reg + 1] + ((const float*)&wq[reg >> 2])[(reg & 3) + 1];
                mcol[st] = fminf(fminf(mcol[st], u), v);   // v_min3
            }
    }

    // ---- 3) reduce: +shsq once; lanes n / n+32 share column
    #pragma unroll
    for (int st = 0; st < 2; ++st) {
        float mm = mcol[st] + shsqv[st];
        mm = fminf(mm, __shfl_xor(mm, 32, 64));
        if (h == 0) wavemin[w * 64 + st * 32 + n] = mm;
    }
    __syncthreads();
    if (tid < 64) {
        const float mm = fminf(fminf(wavemin[tid], wavemin[64 + tid]),
                               fminf(wavemin[128 + tid], wavemin[192 + tid]));
        partial[(b * NCH + chunk) * Sn + half * 64 + tid] = mm;
    }
}

// ------------------------------------------- final min over chunks + MLP head
__global__ __launch_bounds__(512) void mlp_kernel(const float* __restrict__ partial,
                                                  const float* __restrict__ W1,
                                                  const float* __restrict__ b1,
                                                  const float* __restrict__ W2,
                                                  const float* __restrict__ b2,
                                                  float* __restrict__ out) {
    __shared__ float pmin[4][Sn];
    __shared__ float db[Sn];
    __shared__ float hb[Hn];
    __shared__ float part[Cn][32];
    const int b = blockIdx.x, tid = threadIdx.x;

    {
        const int s = tid & 127, g = tid >> 7;
        const float* pp = partial + (b * NCH + g * 4) * Sn + s;
        float m = pp[0];
        #pragma unroll
        for (int c = 1; c < 4; ++c) m = fminf(m, pp[c * Sn]);
        pmin[g][s] = m;
    }
    __syncthreads();
    if (tid < Sn) {
        const float m = fminf(fminf(pmin[0][tid], pmin[1][tid]),
                              fminf(pmin[2][tid], pmin[3][tid]));
        db[tid] = m;
        out[b * Sn + tid] = m;             // distance output
    }
    __syncthreads();

    float a = b1[tid];
    const float4* w1r = (const float4*)(W1 + tid * Sn);
    const float4* dbv = (const float4*)db;
    #pragma unroll
    for (int i = 0; i < Sn / 4; ++i) {
        const float4 wv = w1r[i];
        const float4 dv = dbv[i];
        a = fmaf(dv.x, wv.x, a); a = fmaf(dv.y, wv.y, a);
        a = fmaf(dv.z, wv.z, a); a = fmaf(dv.w, wv.w, a);
    }
    hb[tid] = fmaxf(a, 0.0f);
    __syncthreads();

    if (tid < Cn * 32) {
        const int c = tid >> 5, p = tid & 31;
        float acc = 0.f;
        #pragma unroll
        for (int i = 0; i < Hn / 32; ++i)
            acc = fmaf(hb[p + 32 * i], W2[c * Hn + p + 32 * i], acc);
        part[c][p] = acc;
    }
    __syncthreads();
    if (tid < Cn) {
        float acc = b2[tid];
        #pragma unroll
        for (int p = 0; p < 32; ++p) acc += part[tid][p];
        out[Bn * Sn + b * Cn + tid] = acc; // classification output
    }
}

// ----------------------------------------------------------------- launcher
extern "C" void kernel_launch(void* const* d_in, const int* in_sizes, int n_in,
                              void* d_out, int out_size, void* d_ws, size_t ws_size,
                              hipStream_t stream) {
    const float* x  = (const float*)d_in[0];
    const float* sh = (const float*)d_in[1];
    const float* W1 = (const float*)d_in[2];
    const float* b1 = (const float*)d_in[3];
    const float* W2 = (const float*)d_in[4];
    const float* b2 = (const float*)d_in[5];
    float* out = (float*)d_out;

    char* wsb = (char*)d_ws;
    float*        partial = (float*)wsb;                    // 262144 B
    unsigned int* shb     = (unsigned int*)(wsb + 262144);  //  12288 B
    float*        shsq_g  = (float*)(wsb + 274432);         //    512 B
    float*        wsqT    = (float*)(wsb + 278528);         //   2 MiB (32 x 16 x 1024)
    unsigned int* xg      = (unsigned int*)(wsb + 2375680); //  ~25 MiB (768 x XBP dwords)

    prep_kernel<<<513, 256, 0, stream>>>(x, sh, shb, shsq_g, wsqT, xg);
    dist_kernel<<<Bn * NCH * 2, 256, 0, stream>>>(shb, shsq_g, wsqT, xg, partial);
    mlp_kernel<<<Bn, 512, 0, stream>>>(partial, W1, b1, W2, b2, out);
}

// Round 9
// 97.777 us; speedup vs baseline: 1.4631x; 1.0201x over previous
//
#include <hip/hip_runtime.h>

#define Bn 32
#define Tn 16384
#define Ln 16
#define Sn 128
#define Hn 512
#define Cn 10
#define Kn 48
#define TOUT 16369
#define CH 1024
#define NCH 16
#define XBP 8224   // dwords per (b,ch) row of xbf (8192 + 32 zero pad)

typedef short  s16x8  __attribute__((ext_vector_type(8)));
typedef float  f32x16 __attribute__((ext_vector_type(16)));

static __device__ __forceinline__ unsigned short f2bf(float f) {
    union { float f; unsigned int u; } v; v.f = f;
    unsigned int r = v.u + 0x7FFF + ((v.u >> 16) & 1);   // RNE
    return (unsigned short)(r >> 16);
}
static __device__ __forceinline__ float bf2f(unsigned short b) {
    union { unsigned int u; float f; } v; v.u = ((unsigned int)b) << 16;
    return v.f;
}
static __device__ __forceinline__ unsigned int pk(float a, float b) {
    return (unsigned int)f2bf(a) | ((unsigned int)f2bf(b) << 16);
}
static __device__ __forceinline__ unsigned int pk2(unsigned short a, unsigned short b) {
    return (unsigned int)a | ((unsigned int)b << 16);
}
static __device__ __forceinline__ s16x8 mk_a(unsigned int d0, unsigned int d1,
                                             unsigned int d2, unsigned int d3) {
    union { unsigned int u[4]; s16x8 v; } t;
    t.u[0] = d0; t.u[1] = d1; t.u[2] = d2; t.u[3] = d3;
    return t.v;
}
static __device__ __forceinline__ s16x8 mk_a4(uint4 t) {
    union { uint4 u; s16x8 v; } c; c.u = t; return c.v;
}

// ------------------------------------------------------------------ prologue
// shb: bf16(-2*sh) rows (B-frag order); shsq: fp32 row norms;
// wsqT[b][t&15][t>>4]: window norms transposed, 1e30 tail mask;
// xbf: single-phase bf16(x), zero-padded; also inits out[cls] = b2.
__global__ __launch_bounds__(256) void prep_kernel(const float* __restrict__ x,
                                                   const float* __restrict__ sh,
                                                   const float* __restrict__ b2,
                                                   unsigned int* __restrict__ shb,
                                                   float* __restrict__ shsq_g,
                                                   float* __restrict__ wsqT,
                                                   unsigned int* __restrict__ xbf,
                                                   float* __restrict__ out) {
    const int tid = threadIdx.x;
    if (blockIdx.x == 0) {
        if (tid < 128) {
            const float4* r4 = (const float4*)(sh + tid * Kn);
            float v[48]; float q = 0.f;
            #pragma unroll
            for (int c = 0; c < 12; ++c) {
                const float4 t = r4[c];
                v[4*c] = t.x; v[4*c+1] = t.y; v[4*c+2] = t.z; v[4*c+3] = t.w;
                q = fmaf(t.x, t.x, q); q = fmaf(t.y, t.y, q);
                q = fmaf(t.z, t.z, q); q = fmaf(t.w, t.w, q);
            }
            shsq_g[tid] = q;
            uint4* dst = (uint4*)(shb + tid * 24);
            #pragma unroll
            for (int c = 0; c < 6; ++c) {
                uint4 o;
                o.x = pk(-2.f*v[8*c  ], -2.f*v[8*c+1]);
                o.y = pk(-2.f*v[8*c+2], -2.f*v[8*c+3]);
                o.z = pk(-2.f*v[8*c+4], -2.f*v[8*c+5]);
                o.w = pk(-2.f*v[8*c+6], -2.f*v[8*c+7]);
                dst[c] = o;
            }
        } else if (tid < 224) {
            const int r = tid - 128;             // 96 rows: zero 32-dword pads
            uint4* d = (uint4*)(xbf + r * XBP + 8192);
            const uint4 z = {0u, 0u, 0u, 0u};
            #pragma unroll
            for (int q = 0; q < 8; ++q) d[q] = z;
        } else {
            const int k0 = (tid - 224) * 10;     // init out[cls] = b2 (mlp atomicAdds)
            #pragma unroll
            for (int c = 0; c < Cn; ++c) out[Bn * Sn + k0 + c] = b2[c];
        }
        return;
    }
    // blocks 1..512: (b, 1024-t slab); thread owns 4 t
    const int bid = blockIdx.x - 1;
    const int b   = bid >> 4;
    const int t0  = ((bid & 15) << 10) + 4 * tid;
    float q[4] = {0.f, 0.f, 0.f, 0.f};
    #pragma unroll
    for (int ch = 0; ch < 3; ++ch) {
        const float* xs = x + (b * 3 + ch) * Tn + t0;
        float wv[20];
        if (t0 + 20 <= Tn) {
            const float4* x4 = (const float4*)xs;
            #pragma unroll
            for (int c = 0; c < 5; ++c) {
                const float4 t = x4[c];
                wv[4*c] = t.x; wv[4*c+1] = t.y; wv[4*c+2] = t.z; wv[4*c+3] = t.w;
            }
        } else {
            #pragma unroll
            for (int k = 0; k < 20; ++k) wv[k] = (t0 + k < Tn) ? xs[k] : 0.f;
        }
        float s = 0.f;
        #pragma unroll
        for (int l = 0; l < 16; ++l) s = fmaf(wv[l], wv[l], s);
        q[0] += s;
        #pragma unroll
        for (int j = 1; j < 4; ++j) {
            s = s - wv[j-1]*wv[j-1] + wv[j+15]*wv[j+15];
            q[j] += s;
        }
        uint2 o = { pk(wv[0], wv[1]), pk(wv[2], wv[3]) };
        *(uint2*)(xbf + (b * 3 + ch) * XBP + (t0 >> 1)) = o;
    }
    const int r0 = t0 & 15, col = t0 >> 4;
    float* wrow = wsqT + b * 16384 + col;
    #pragma unroll
    for (int c = 0; c < 4; ++c)
        wrow[(r0 + c) * 1024] = (t0 + c >= TOUT) ? 1e30f : q[c];
}

// ---------------------------------------------------------------- distance
// Per wave: 6 aligned dwordx4 loads give a 16-elem window u[8] per channel;
// all 8 tiles' A-frags are static slices (even rr) or v_alignbit (odd rr).
// winsq + shsq are FOLDED INTO the MFMA as a 4th K-channel (hi/lo bf16 split)
// -> epilogue is pure min3; no wq arrays, no hoisting spill hazard.
__global__ __launch_bounds__(256, 3) void dist_kernel(const unsigned int* __restrict__ shb,
                                                      const float* __restrict__ shsq_g,
                                                      const float* __restrict__ wsqT,
                                                      const unsigned int* __restrict__ xbf,
                                                      float* __restrict__ partial) {
    __shared__ float wavemin[4 * 64];

    const int tid   = threadIdx.x;
    const int b     = blockIdx.x >> 5;
    const int rem   = blockIdx.x & 31;
    const int chunk = rem >> 1;
    const int half  = rem & 1;                   // S-half: columns half*64 .. +63
    const int tb    = chunk * CH;
    const int lane  = tid & 63;
    const int w     = tid >> 6;
    const int n     = lane & 31;
    const int h     = lane >> 5;

    // ---- B-fragments: 3 data channels + winsq/shsq channel b4
    s16x8 bfr[3][2], b4[2];
    #pragma unroll
    for (int st = 0; st < 2; ++st) {
        const int s = half * 64 + st * 32 + n;
        const uint4* base = (const uint4*)(shb + s * 24);
        #pragma unroll
        for (int kk = 0; kk < 3; ++kk) {
            const uint4 t = base[kk * 2 + h];
            bfr[kk][st] = mk_a(t.x, t.y, t.z, t.w);
        }
        const float q = shsq_g[s];
        const unsigned short qh = f2bf(q);
        const unsigned short ql = f2bf(q - bf2f(qh));
        b4[st] = h ? mk_a(0u, 0u, 0u, 0u)
                   : mk_a(0x3F803F80u, pk2(qh, ql), 0u, 0u);
    }

    // ---- rr-invariant 16-elem bf16 window per channel (16-B aligned loads)
    unsigned int u[3][8];
    {
        const int D0 = (tb >> 1) + 4 * (w & 1) + ((w >> 1) << 8) + 8 * n + 4 * h;
        #pragma unroll
        for (int ch = 0; ch < 3; ++ch) {
            const unsigned int* xr = xbf + (b * 3 + ch) * XBP + D0;
            const uint4 lo = *(const uint4*)(xr);
            const uint4 hi = *(const uint4*)(xr + 4);
            u[ch][0] = lo.x; u[ch][1] = lo.y; u[ch][2] = lo.z; u[ch][3] = lo.w;
            u[ch][4] = hi.x; u[ch][5] = hi.y; u[ch][6] = hi.z; u[ch][7] = hi.w;
        }
    }

    // ---- main loop: 8 tiles, 8 MFMA each (4 per st incl. the w/shsq channel)
    float mcol[2] = {1e30f, 1e30f};
    const f32x16 zero16 = {0.f, 0.f, 0.f, 0.f, 0.f, 0.f, 0.f, 0.f,
                           0.f, 0.f, 0.f, 0.f, 0.f, 0.f, 0.f, 0.f};
    const int   base_t = 8 * (w & 1) + ((w >> 1) << 9);
    const float* wbase = wsqT + b * 16384 + (tb >> 4) + n;

    #pragma unroll
    for (int rr = 0; rr < 8; ++rr) {
        const int i = base_t + rr;
        s16x8 a[3];
        #pragma unroll
        for (int ch = 0; ch < 3; ++ch) {
            if ((rr & 1) == 0) {
                a[ch] = mk_a(u[ch][rr/2], u[ch][rr/2+1], u[ch][rr/2+2], u[ch][rr/2+3]);
            } else {
                unsigned int d[4];
                #pragma unroll
                for (int k = 0; k < 4; ++k)
                    d[k] = (u[ch][rr/2 + k] >> 16) | (u[ch][rr/2 + k + 1] << 16);
                a[ch] = mk_a(d[0], d[1], d[2], d[3]);
            }
        }
        // winsq channel: per-lane scalar load + hi/lo bf16 split
        const float wv = wbase[(i & 15) * 1024 + ((i >> 9) << 5)];
        const unsigned short wh = f2bf(wv);
        const unsigned short wl = f2bf(wv - bf2f(wh));
        const s16x8 a4 = h ? mk_a(0u, 0u, 0u, 0u)
                           : mk_a(pk2(wh, wl), 0x3F803F80u, 0u, 0u);

        #pragma unroll
        for (int st = 0; st < 2; ++st) {
            f32x16 acc;
            acc = __builtin_amdgcn_mfma_f32_32x32x16_bf16(a[0], bfr[0][st], zero16, 0, 0, 0);
            acc = __builtin_amdgcn_mfma_f32_32x32x16_bf16(a[1], bfr[1][st], acc, 0, 0, 0);
            acc = __builtin_amdgcn_mfma_f32_32x32x16_bf16(a[2], bfr[2][st], acc, 0, 0, 0);
            acc = __builtin_amdgcn_mfma_f32_32x32x16_bf16(a4,   b4[st],    acc, 0, 0, 0);
            #pragma unroll
            for (int reg = 0; reg < 16; reg += 2)
                mcol[st] = fminf(fminf(mcol[st], acc[reg]), acc[reg + 1]);   // v_min3
        }
    }

    // ---- reduce: lanes n / n+32 share column
    #pragma unroll
    for (int st = 0; st < 2; ++st) {
        float mm = mcol[st];
        mm = fminf(mm, __shfl_xor(mm, 32, 64));
        if (h == 0) wavemin[w * 64 + st * 32 + n] = mm;
    }
    __syncthreads();
    if (tid < 64) {
        const float mm = fminf(fminf(wavemin[tid], wavemin[64 + tid]),
                               fminf(wavemin[128 + tid], wavemin[192 + tid]));
        partial[(b * NCH + chunk) * Sn + half * 64 + tid] = mm;
    }
}

// ------------------------- final min + MLP, H split over 4 blocks per batch
__global__ __launch_bounds__(512) void mlp_kernel(const float* __restrict__ partial,
                                                  const float* __restrict__ W1,
                                                  const float* __restrict__ b1,
                                                  const float* __restrict__ W2,
                                                  float* __restrict__ out) {
    __shared__ float pmin[4][Sn];
    __shared__ float db[Sn];
    __shared__ float hb[128];
    __shared__ float part[Cn][32];
    const int b = blockIdx.x >> 2, g = blockIdx.x & 3, tid = threadIdx.x;

    {
        const int s = tid & 127, cg = tid >> 7;
        const float* pp = partial + (b * NCH + cg * 4) * Sn + s;
        float m = pp[0];
        #pragma unroll
        for (int c = 1; c < 4; ++c) m = fminf(m, pp[c * Sn]);
        pmin[cg][s] = m;
    }
    __syncthreads();
    if (tid < Sn) {
        const float m = fminf(fminf(pmin[0][tid], pmin[1][tid]),
                              fminf(pmin[2][tid], pmin[3][tid]));
        db[tid] = m;
        if (g == 0) out[b * Sn + tid] = m;     // distance output
    }
    __syncthreads();

    if (tid < 128) {                            // h rows g*128 .. +127
        const int hrow = g * 128 + tid;
        float a = b1[hrow];
        const float4* w1r = (const float4*)(W1 + hrow * Sn);
        const float4* dbv = (const float4*)db;
        #pragma unroll
        for (int i = 0; i < Sn / 4; ++i) {
            const float4 wv = w1r[i];
            const float4 dv = dbv[i];
            a = fmaf(dv.x, wv.x, a); a = fmaf(dv.y, wv.y, a);
            a = fmaf(dv.z, wv.z, a); a = fmaf(dv.w, wv.w, a);
        }
        hb[tid] = fmaxf(a, 0.0f);
    }
    __syncthreads();

    if (tid < Cn * 32) {
        const int c = tid >> 5, p = tid & 31;
        float acc = 0.f;
        #pragma unroll
        for (int k = 0; k < 4; ++k)
            acc = fmaf(hb[p + 32 * k], W2[c * Hn + g * 128 + p + 32 * k], acc);
        part[c][p] = acc;
    }
    __syncthreads();
    if (tid < Cn) {
        float acc = 0.f;
        #pragma unroll
        for (int p = 0; p < 32; ++p) acc += part[tid][p];
        atomicAdd(&out[Bn * Sn + b * Cn + tid], acc);   // b2 pre-added by prep
    }
}

// ----------------------------------------------------------------- launcher
extern "C" void kernel_launch(void* const* d_in, const int* in_sizes, int n_in,
                              void* d_out, int out_size, void* d_ws, size_t ws_size,
                              hipStream_t stream) {
    const float* x  = (const float*)d_in[0];
    const float* sh = (const float*)d_in[1];
    const float* W1 = (const float*)d_in[2];
    const float* b1 = (const float*)d_in[3];
    const float* W2 = (const float*)d_in[4];
    const float* b2 = (const float*)d_in[5];
    float* out = (float*)d_out;

    char* wsb = (char*)d_ws;
    float*        partial = (float*)wsb;                    // 262144 B
    unsigned int* shb     = (unsigned int*)(wsb + 262144);  //  12288 B
    float*        shsq_g  = (float*)(wsb + 274432);         //    512 B
    float*        wsqT    = (float*)(wsb + 278528);         //   2 MiB
    unsigned int* xbf     = (unsigned int*)(wsb + 2375680); //   3.2 MiB

    prep_kernel<<<513, 256, 0, stream>>>(x, sh, b2, shb, shsq_g, wsqT, xbf, out);
    dist_kernel<<<Bn * NCH * 2, 256, 0, stream>>>(shb, shsq_g, wsqT, xbf, partial);
    mlp_kernel<<<Bn * 4, 512, 0, stream>>>(partial, W1, b1, W2, out);
}